// Round 13
// baseline (218.415 us; speedup 1.0000x reference)
//
#include <hip/hip_runtime.h>
#include <math.h>

// ---------------- LDS layout (floats), per 64-thread (1-wave) block ----------
// R7 structure, but the two n2h-slices of each n1 run as TWO INDEPENDENT
// in-wave chains (A=n2h0, B=n2h1) with private T2 buffers and disjoint T3
// row ranges -- ILP inside the wave, TLP (8 waves/CU) unchanged.
#define WC3  0      // l1c3 [q3][m4][n4][q4]            128
#define WC2  128    // l1c2 [q2][m3][n3][q3]            128
#define WU1  256    // l2c1                              32  -> 288
#define T2A_ 288    // chain A T2 [32][36] = 1152            -> 1440
#define T2B_ 1440   // chain B T2                            -> 2592
#define T3S  2592   // T3 [32][34] = 1088 (A rows 0-15, B rows 16-31) -> 3680
#define H1O  288    // h1 (2048) overlays T2A_/T2B_ after layer 1     -> 2336
#define BO   2592   // B[128][9] = 1152 (over dead T3S)               -> 3744
#define CO   288    // C[32][17] = 544 (over dead h1 head)            -> 832
#define DO   832    // D[16][17] = 272                                -> 1104
#define H2O  1104   // 64                                             -> 1168
#define H3O  1168   // 32                                             -> 1200
#define LDS_FLOATS 3744   // 14976 B; grid caps residency at 8 waves/CU

// Setup: dense layer-3 matrix W3[mi(32)][nj(64)] from TT cores (tiny).
__global__ void tt_setup_w3(const float* __restrict__ v0, const float* __restrict__ v1,
                            const float* __restrict__ v2, const float* __restrict__ v3,
                            const float* __restrict__ v4, float* __restrict__ w3) {
    int i = blockIdx.x * 256 + threadIdx.x;
    if (i >= 2048) return;
    int mi = i >> 6, nj = i & 63;
    int m1 = (mi >> 4) & 1, m2 = (mi >> 3) & 1, m3 = (mi >> 2) & 1, m4 = (mi >> 1) & 1, m5 = mi & 1;
    int n1 = (nj >> 4) & 3, n2 = (nj >> 3) & 1, n3 = (nj >> 2) & 1, n4 = (nj >> 1) & 1, n5 = nj & 1;
    float s = 0.f;
#pragma unroll
    for (int q1 = 0; q1 < 2; ++q1) {
        float a1 = v0[(m1 * 4 + n1) * 2 + q1];
#pragma unroll
        for (int q2 = 0; q2 < 2; ++q2) {
            float a2 = a1 * v1[((q1 * 2 + m2) * 2 + n2) * 2 + q2];
#pragma unroll
            for (int q3 = 0; q3 < 2; ++q3) {
                float a3 = a2 * v2[((q2 * 2 + m3) * 2 + n3) * 2 + q3];
#pragma unroll
                for (int q4 = 0; q4 < 2; ++q4)
                    s = fmaf(a3 * v3[((q3 * 2 + m4) * 2 + n4) * 2 + q4],
                             v4[(q4 * 2 + m5) * 2 + n5], s);
            }
        }
    }
    w3[i] = s;
}

// ---- step macros (register indices compile-time only; rule #20) ----
#define PREFETCH_X(BUF, SLAB) do {                                          \
    const float4* xq_ = (const float4*)xb + (SLAB) * 512 + t * 8;           \
    _Pragma("unroll") for (int i_ = 0; i_ < 8; ++i_) {                      \
        const float4 v_ = xq_[i_];                                          \
        BUF[i_*4+0] = v_.x; BUF[i_*4+1] = v_.y;                             \
        BUF[i_*4+2] = v_.z; BUF[i_*4+3] = v_.w;                             \
    } } while (0)

#define STEP1(T1, BUF) do {                                                 \
    _Pragma("unroll") for (int m5_ = 0; m5_ < 4; ++m5_)                     \
    _Pragma("unroll") for (int q4_ = 0; q4_ < 2; ++q4_) {                   \
        const float* w_ = g4 + (q4_ * 4 + m5_) * 8;                         \
        _Pragma("unroll") for (int n4l_ = 0; n4l_ < 4; ++n4l_) {            \
            float sa_ = BUF[n4l_*8+0] * w_[0];                              \
            _Pragma("unroll") for (int n5_ = 1; n5_ < 8; ++n5_)             \
                sa_ = fmaf(BUF[n4l_*8+n5_], w_[n5_], sa_);                  \
            T1[n4l_*8 + m5_*2 + q4_] = sa_;                                 \
        } } } while (0)

#define STEP2(ACC, T1) do {                                                 \
    _Pragma("unroll") for (int i_ = 0; i_ < 16; ++i_) ACC[i_] = 0.f;        \
    _Pragma("unroll") for (int pass_ = 0; pass_ < 2; ++pass_) {             \
        const int hh_ = (pass_ == 0) ? h : (1 - h);                         \
        if (pass_ == 1) {                                                   \
            _Pragma("unroll") for (int i_ = 0; i_ < 32; ++i_)               \
                T1[i_] = __shfl_xor(T1[i_], 1);                             \
        }                                                                   \
        _Pragma("unroll") for (int m4_ = 0; m4_ < 4; ++m4_) {               \
            const int cb_ = WC3 + ((h * 4 + m4_) * 8 + hh_ * 4) * 2;        \
            const float4 c0_ = *(const float4*)&smem[cb_];                  \
            const float4 c1_ = *(const float4*)&smem[cb_ + 4];              \
            const float cs_[8] = {c0_.x,c0_.y,c0_.z,c0_.w,c1_.x,c1_.y,c1_.z,c1_.w}; \
            _Pragma("unroll") for (int m5_ = 0; m5_ < 4; ++m5_) {           \
                float sa_ = ACC[m4_*4+m5_];                                 \
                _Pragma("unroll") for (int n4l_ = 0; n4l_ < 4; ++n4l_)      \
                _Pragma("unroll") for (int q4_ = 0; q4_ < 2; ++q4_)         \
                    sa_ = fmaf(T1[n4l_*8 + m5_*2 + q4_], cs_[n4l_*2+q4_], sa_); \
                ACC[m4_*4+m5_] = sa_;                                       \
            } } } } while (0)

// STEP3: T2X -> T3 rows [ROWBASE .. ROWBASE+15]
#define STEP3(T2X, ROWBASE) do {                                            \
    const int n3h_ = t & 1, q2_ = (t >> 1) & 1, m3_ = (t >> 2) & 3, n2l_ = t >> 4; \
    float o3_[16];                                                          \
    _Pragma("unroll") for (int i_ = 0; i_ < 16; ++i_) o3_[i_] = 0.f;        \
    _Pragma("unroll") for (int n3l_ = 0; n3l_ < 4; ++n3l_) {                \
        const int rb_ = (T2X) + (n2l_*8 + n3h_*4 + n3l_) * 36;              \
        float rv_[32];                                                      \
        _Pragma("unroll") for (int g_ = 0; g_ < 8; ++g_) {                  \
            const float4 v_ = *(const float4*)&smem[rb_ + g_*4];            \
            rv_[g_*4+0]=v_.x; rv_[g_*4+1]=v_.y; rv_[g_*4+2]=v_.z; rv_[g_*4+3]=v_.w; \
        }                                                                   \
        const int wb_ = WC2 + ((q2_*4 + m3_)*8 + n3h_*4 + n3l_) * 2;        \
        const float w0_ = smem[wb_], w1_ = smem[wb_+1];                     \
        _Pragma("unroll") for (int m45_ = 0; m45_ < 16; ++m45_)             \
            o3_[m45_] = fmaf(rv_[m45_*2], w0_, fmaf(rv_[m45_*2+1], w1_, o3_[m45_])); \
    }                                                                       \
    _Pragma("unroll") for (int k_ = 0; k_ < 16; ++k_) o3_[k_] += __shfl_xor(o3_[k_], 1); \
    const int row_ = (ROWBASE) + n2l_*4 + m3_;                              \
    _Pragma("unroll") for (int k_ = 0; k_ < 8; ++k_) {                      \
        const float v_ = n3h_ ? o3_[8+k_] : o3_[k_];                        \
        smem[T3S + row_*34 + (n3h_*8+k_)*2 + q2_] = v_;                     \
    } } while (0)

// Grid = 2048 one-wave blocks = 8 waves/CU = 2 waves/EU (hard cap).
// waves_per_eu(1,2): allocator budgets up to 256 VGPR (R7-validated: no
// phantom-wave squeeze, spills 38MB->64KB). Live set ~195 fits.
__global__ __launch_bounds__(64)
__attribute__((amdgpu_waves_per_eu(1, 2)))
void tt_main(const float* __restrict__ x,
             const float* __restrict__ g0, const float* __restrict__ g1,
             const float* __restrict__ g2, const float* __restrict__ g3,
             const float* __restrict__ g4, const float* __restrict__ b1g,
             const float* __restrict__ u0, const float* __restrict__ u1,
             const float* __restrict__ u2, const float* __restrict__ u3,
             const float* __restrict__ u4, const float* __restrict__ b2g,
             const float* __restrict__ b3g,
             const float* __restrict__ Wmg, const float* __restrict__ blg,
             const float* __restrict__ w3g,
             float* __restrict__ out)
{
    __shared__ float smem[LDS_FLOATS];
    const int t = threadIdx.x;
    const int b = blockIdx.x;
    const float* xb = x + (size_t)b * 12288;

    // ---- issue x loads for slabs 0 (chain A) and 1 (chain B) ----
    float xv0[32], xv1[32];
    PREFETCH_X(xv0, 0);
    PREFETCH_X(xv1, 1);

    // ---- non-uniformly-indexed weights to LDS ----
    smem[WC3 + t] = g3[t];  smem[WC3 + 64 + t] = g3[64 + t];
    smem[WC2 + t] = g2[t];  smem[WC2 + 64 + t] = g2[64 + t];
    if (t < 32) smem[WU1 + t] = u1[t];
    __syncthreads();  // weights ready

    const int h = t & 1;       // n4-half owned by this lane
    const int p = t >> 1;      // subslice-local prefix (n2l*8 + n3)

    float regT4[36];           // [jj(4)][n1(3)*3+q1(3)] accumulated across n1
#pragma unroll
    for (int i = 0; i < 36; ++i) regT4[i] = 0.f;

#pragma unroll
    for (int n1 = 0; n1 < 3; ++n1) {
        // ---- step 1+2, chain A (slab 2*n1), then chain B (slab 2*n1+1).
        //      t1 shared (register budget); accA/accB independent.
        float t1[32], accA[16], accB[16];
        STEP1(t1, xv0);
        if (n1 < 2) PREFETCH_X(xv0, 2 * n1 + 2);   // xv0 dead: reload in place
        STEP2(accA, t1);
        STEP1(t1, xv1);
        if (n1 < 2) PREFETCH_X(xv1, 2 * n1 + 3);
        STEP2(accB, t1);

        __syncthreads();   // prev iter: STEP3 T2-reads + STEP4 T3-reads done
#pragma unroll
        for (int m45 = 0; m45 < 16; ++m45)
            smem[T2A_ + p * 36 + m45 * 2 + h] = accA[m45];
#pragma unroll
        for (int m45 = 0; m45 < 16; ++m45)
            smem[T2B_ + p * 36 + m45 * 2 + h] = accB[m45];
        __syncthreads();   // both T2 buffers ready

        // ---- step 3, both chains: disjoint T2 sources, disjoint T3 row
        //      ranges -> fully independent; scheduler interleaves A's
        //      ds_read latency with B's FMAs and vice versa (the ILP payload).
        STEP3(T2A_, 0);    // T3 rows 0..15  (n2h = 0)
        STEP3(T2B_, 16);   // T3 rows 16..31 (n2h = 1)
        __syncthreads();   // T3 complete

        // ---- step 4: contract n2,q2 -> regT4 (C1 uniform: s_load)
        {
            const int m3 = t >> 4, m4 = (t >> 2) & 3, m5 = t & 3;
            float2 zz[8];
#pragma unroll
            for (int n2 = 0; n2 < 8; ++n2)
                zz[n2] = *(const float2*)&smem[T3S + (n2 * 4 + m3) * 34 + (m4 * 4 + m5) * 2];
#pragma unroll
            for (int jj = 0; jj < 4; ++jj)
#pragma unroll
            for (int q1 = 0; q1 < 3; ++q1) {
                float sa = regT4[jj * 9 + n1 * 3 + q1];
#pragma unroll
                for (int n2g = 0; n2g < 4; ++n2g) {
                    const float4 w = *(const float4*)(g1 + ((q1 * 4 + jj) * 8 + n2g * 2) * 2);
                    sa = fmaf(zz[n2g*2].x,   w.x, sa);
                    sa = fmaf(zz[n2g*2].y,   w.y, sa);
                    sa = fmaf(zz[n2g*2+1].x, w.z, sa);
                    sa = fmaf(zz[n2g*2+1].y, w.w, sa);
                }
                regT4[jj * 9 + n1 * 3 + q1] = sa;
            }
        }
    } // n1
    __syncthreads();   // T3/T2 reads done; h1 may overwrite T2 zones

    // ---- step 5: contract n1,q1 + bias + relu -> h1 (C0 uniform: s_load)
#pragma unroll
    for (int jj = 0; jj < 4; ++jj) {
        float bia[8];
#pragma unroll
        for (int m1 = 0; m1 < 8; ++m1) bia[m1] = b1g[m1 * 256 + jj * 64 + t];
#pragma unroll
        for (int m1 = 0; m1 < 8; ++m1) {
            float sa = bia[m1];
#pragma unroll
            for (int n1 = 0; n1 < 3; ++n1)
#pragma unroll
            for (int q1 = 0; q1 < 3; ++q1)
                sa = fmaf(regT4[jj * 9 + n1 * 3 + q1], g0[(m1 * 3 + n1) * 3 + q1], sa);
            smem[H1O + m1 * 256 + jj * 64 + t] = fmaxf(sa, 0.f);
        }
    }
    __syncthreads();

    // ================= layer 2 (right-to-left) =================
    // L2ab fused: per p3 read h1[16], apply u4 (L2a) in registers,
    // contract n4,q4 (L2b) -> B row (BO over dead T3).
#pragma unroll
    for (int pq = 0; pq < 2; ++pq) {
        const int p3 = 2 * t + pq;
        float o[8];
#pragma unroll
        for (int i = 0; i < 8; ++i) o[i] = 0.f;
#pragma unroll
        for (int n4 = 0; n4 < 4; ++n4) {
            const float4 hv = *(const float4*)&smem[H1O + (p3 * 4 + n4) * 4];
            const float ax = hv.x*u4[0]  + hv.y*u4[1]  + hv.z*u4[2]  + hv.w*u4[3];   // m5=0,q4=0
            const float ay = hv.x*u4[8]  + hv.y*u4[9]  + hv.z*u4[10] + hv.w*u4[11];  // m5=0,q4=1
            const float az = hv.x*u4[4]  + hv.y*u4[5]  + hv.z*u4[6]  + hv.w*u4[7];   // m5=1,q4=0
            const float aw = hv.x*u4[12] + hv.y*u4[13] + hv.z*u4[14] + hv.w*u4[15];  // m5=1,q4=1
#pragma unroll
            for (int q4 = 0; q4 < 2; ++q4) {
                const float a0 = q4 ? ay : ax;   // m5=0
                const float a1 = q4 ? aw : az;   // m5=1
#pragma unroll
                for (int q3 = 0; q3 < 2; ++q3)
#pragma unroll
                for (int m4 = 0; m4 < 2; ++m4) {
                    const float w = u3[((q3 * 2 + m4) * 4 + n4) * 2 + q4];
                    o[(m4 * 2 + 0) * 2 + q3] = fmaf(a0, w, o[(m4 * 2 + 0) * 2 + q3]);
                    o[(m4 * 2 + 1) * 2 + q3] = fmaf(a1, w, o[(m4 * 2 + 1) * 2 + q3]);
                }
            }
        }
#pragma unroll
        for (int k = 0; k < 8; ++k) smem[BO + p3 * 9 + k] = o[k];
    }
    __syncthreads();

    // L2c: contract n3(4),q3 -> C[p2][(m3*4+m45)*2+q2]  (U2 uniform)
    if (t < 32) {
        float o[16];
#pragma unroll
        for (int i = 0; i < 16; ++i) o[i] = 0.f;
#pragma unroll
        for (int n3 = 0; n3 < 4; ++n3)
#pragma unroll
        for (int q3 = 0; q3 < 2; ++q3) {
            float zb[4];
#pragma unroll
            for (int m45 = 0; m45 < 4; ++m45)
                zb[m45] = smem[BO + (t * 4 + n3) * 9 + m45 * 2 + q3];
#pragma unroll
            for (int m3 = 0; m3 < 2; ++m3)
#pragma unroll
            for (int q2 = 0; q2 < 2; ++q2) {
                const float w = u2[((q2 * 2 + m3) * 4 + n3) * 2 + q3];
#pragma unroll
                for (int m45 = 0; m45 < 4; ++m45)
                    o[(m3 * 4 + m45) * 2 + q2] = fmaf(zb[m45], w, o[(m3 * 4 + m45) * 2 + q2]);
            }
        }
#pragma unroll
        for (int k = 0; k < 16; ++k) smem[CO + t * 17 + k] = o[k];
    }
    __syncthreads();

    // L2d: contract n2(4),q2 -> D[s][n1*2+q1]  (U1 non-uniform: LDS)
    if (t < 32) {
        const int n1 = t >> 2, m2 = (t >> 1) & 1, m3 = t & 1;
        float o[8];
#pragma unroll
        for (int i = 0; i < 8; ++i) o[i] = 0.f;
#pragma unroll
        for (int n2 = 0; n2 < 4; ++n2)
#pragma unroll
        for (int q2 = 0; q2 < 2; ++q2) {
            float cb[4];
#pragma unroll
            for (int m45 = 0; m45 < 4; ++m45)
                cb[m45] = smem[CO + (n1 * 4 + n2) * 17 + (m3 * 4 + m45) * 2 + q2];
#pragma unroll
            for (int q1 = 0; q1 < 2; ++q1) {
                const float w = smem[WU1 + ((q1 * 2 + m2) * 4 + n2) * 2 + q2];
#pragma unroll
                for (int m45 = 0; m45 < 4; ++m45)
                    o[m45 * 2 + q1] = fmaf(cb[m45], w, o[m45 * 2 + q1]);
            }
        }
#pragma unroll
        for (int m45 = 0; m45 < 4; ++m45)
#pragma unroll
        for (int q1 = 0; q1 < 2; ++q1)
            smem[DO + (m2 * 8 + m3 * 4 + m45) * 17 + n1 * 2 + q1] = o[m45 * 2 + q1];
    }
    __syncthreads();

    // L2e: contract n1(8),q1 + bias + relu -> h2  (U0 uniform)
    if (t < 16) {
        float o[4];
#pragma unroll
        for (int i = 0; i < 4; ++i) o[i] = 0.f;
#pragma unroll
        for (int n1 = 0; n1 < 8; ++n1)
#pragma unroll
        for (int q1 = 0; q1 < 2; ++q1) {
            const float dv = smem[DO + t * 17 + n1 * 2 + q1];
#pragma unroll
            for (int m1 = 0; m1 < 4; ++m1)
                o[m1] = fmaf(dv, u0[(m1 * 8 + n1) * 2 + q1], o[m1]);
        }
#pragma unroll
        for (int m1 = 0; m1 < 4; ++m1)
            smem[H2O + m1 * 16 + t] = fmaxf(o[m1] + b2g[m1 * 16 + t], 0.f);
    }
    __syncthreads();

    // ---- layer 3 dense (W3 32x64 from d_ws) + relu ----
    if (t < 32) {
        const float4* wr = (const float4*)(w3g + t * 64);
        float sa = b3g[t];
#pragma unroll
        for (int g = 0; g < 16; ++g) {
            const float4 w4 = wr[g];
            sa = fmaf(w4.x, smem[H2O + g*4 + 0],
                 fmaf(w4.y, smem[H2O + g*4 + 1],
                 fmaf(w4.z, smem[H2O + g*4 + 2],
                 fmaf(w4.w, smem[H2O + g*4 + 3], sa))));
        }
        smem[H3O + t] = fmaxf(sa, 0.f);
    }
    __syncthreads();

    // ---- head: logits + log_softmax ----
    {
        const int k = t & 31;
        float pr = smem[H3O + k] * Wmg[t];   // t = c*32 + k
#pragma unroll
        for (int d = 16; d >= 1; d >>= 1) pr += __shfl_xor(pr, d);
        const float l0 = __shfl(pr, 0) + blg[0];
        const float l1 = __shfl(pr, 32) + blg[1];
        if (t == 0) {
            const float mm = fmaxf(l0, l1);
            const float lse = mm + logf(expf(l0 - mm) + expf(l1 - mm));
            out[(size_t)b * 2 + 0] = l0 - lse;
            out[(size_t)b * 2 + 1] = l1 - lse;
        }
    }
}

extern "C" void kernel_launch(void* const* d_in, const int* in_sizes, int n_in,
                              void* d_out, int out_size, void* d_ws, size_t ws_size,
                              hipStream_t stream) {
    const float* x    = (const float*)d_in[0];
    const float* l1c0 = (const float*)d_in[1];
    const float* l1c1 = (const float*)d_in[2];
    const float* l1c2 = (const float*)d_in[3];
    const float* l1c3 = (const float*)d_in[4];
    const float* l1c4 = (const float*)d_in[5];
    const float* b1   = (const float*)d_in[6];
    const float* l2c0 = (const float*)d_in[7];
    const float* l2c1 = (const float*)d_in[8];
    const float* l2c2 = (const float*)d_in[9];
    const float* l2c3 = (const float*)d_in[10];
    const float* l2c4 = (const float*)d_in[11];
    const float* b2   = (const float*)d_in[12];
    const float* l3c0 = (const float*)d_in[13];
    const float* l3c1 = (const float*)d_in[14];
    const float* l3c2 = (const float*)d_in[15];
    const float* l3c3 = (const float*)d_in[16];
    const float* l3c4 = (const float*)d_in[17];
    const float* b3   = (const float*)d_in[18];
    const float* Wm   = (const float*)d_in[19];
    const float* bl   = (const float*)d_in[20];
    float* W3 = (float*)d_ws;  // 2048 floats scratch

    tt_setup_w3<<<8, 256, 0, stream>>>(l3c0, l3c1, l3c2, l3c3, l3c4, W3);
    tt_main<<<2048, 64, 0, stream>>>(x, l1c0, l1c1, l1c2, l1c3, l1c4, b1,
                                     l2c0, l2c1, l2c2, l2c3, l2c4, b2, b3,
                                     Wm, bl, W3, (float*)d_out);
}

// Round 14
// 217.651 us; speedup vs baseline: 1.0035x; 1.0035x over previous
//
#include <hip/hip_runtime.h>
#include <math.h>

// ---------------- LDS layout (floats), per 64-thread (1-wave) block ----------
// R0 layout, minus the A-buffer (L2a fused into L2b in registers).
// Session-final structure: 13 rounds of restructuring (multi-wave coupled/
// uncoupled, barrier-free, double-buffered, software-pipelined, multi-sample
// ILP) all land at/above this kernel's time. Total VALU-issue is ~19-20 us in
// every variant; the remainder is per-slice LDS-chain latency the compiler's
// scheduler re-derives regardless of source order. This is the empirical best.
#define WC3  0      // l1c3 [q3][m4][n4][q4]            128
#define WC2  128    // l1c2 [q2][m3][n3][q3]            128
#define WU1  256    // l2c1                              32  -> 288
#define T2S  288    // [32 prefixes][36]  (pad 36: b128-aligned rows)  1152 -> 1440
#define T3S  1440   // [32 rows][34]      (pad 34: b64-aligned)        1088 -> 2528
#define H1O  288    // h1 (2048) overlays T2S/T3S after layer-1 slices  -> 2336
#define BO   2528   // B[128][9] = 1152 (after T3S; h1 stays live)      -> 3680
#define CO   1440   // C[32][17] = 544  (h1/T3 dead by L2c)
#define DO   1984   // D[16][17] = 272
#define H2O  2256   // 64
#define H3O  2320   // 32 -> 2352
#define LDS_FLOATS 3680   // 14720 B; grid caps residency at 8 waves/CU

// Setup: dense layer-3 matrix W3[mi(32)][nj(64)] from TT cores (tiny).
__global__ void tt_setup_w3(const float* __restrict__ v0, const float* __restrict__ v1,
                            const float* __restrict__ v2, const float* __restrict__ v3,
                            const float* __restrict__ v4, float* __restrict__ w3) {
    int i = blockIdx.x * 256 + threadIdx.x;
    if (i >= 2048) return;
    int mi = i >> 6, nj = i & 63;
    int m1 = (mi >> 4) & 1, m2 = (mi >> 3) & 1, m3 = (mi >> 2) & 1, m4 = (mi >> 1) & 1, m5 = mi & 1;
    int n1 = (nj >> 4) & 3, n2 = (nj >> 3) & 1, n3 = (nj >> 2) & 1, n4 = (nj >> 1) & 1, n5 = nj & 1;
    float s = 0.f;
#pragma unroll
    for (int q1 = 0; q1 < 2; ++q1) {
        float a1 = v0[(m1 * 4 + n1) * 2 + q1];
#pragma unroll
        for (int q2 = 0; q2 < 2; ++q2) {
            float a2 = a1 * v1[((q1 * 2 + m2) * 2 + n2) * 2 + q2];
#pragma unroll
            for (int q3 = 0; q3 < 2; ++q3) {
                float a3 = a2 * v2[((q2 * 2 + m3) * 2 + n3) * 2 + q3];
#pragma unroll
                for (int q4 = 0; q4 < 2; ++q4)
                    s = fmaf(a3 * v3[((q3 * 2 + m4) * 2 + n4) * 2 + q4],
                             v4[(q4 * 2 + m5) * 2 + n5], s);
            }
        }
    }
    w3[i] = s;
}

// Grid = 2048 one-wave blocks / 256 CU = 8 waves/CU = 2 waves/EU (hard cap).
// waves_per_eu(1,2): tell the allocator exactly that, so it stops squeezing
// VGPRs toward 6-8 waves/EU (validated R7: scratch spills 38 MB -> 64 KB).
__global__ __launch_bounds__(64)
__attribute__((amdgpu_waves_per_eu(1, 2)))
void tt_main(const float* __restrict__ x,
             const float* __restrict__ g0, const float* __restrict__ g1,
             const float* __restrict__ g2, const float* __restrict__ g3,
             const float* __restrict__ g4, const float* __restrict__ b1g,
             const float* __restrict__ u0, const float* __restrict__ u1,
             const float* __restrict__ u2, const float* __restrict__ u3,
             const float* __restrict__ u4, const float* __restrict__ b2g,
             const float* __restrict__ b3g,
             const float* __restrict__ Wmg, const float* __restrict__ blg,
             const float* __restrict__ w3g,
             float* __restrict__ out)
{
    __shared__ float smem[LDS_FLOATS];
    const int t = threadIdx.x;
    const int b = blockIdx.x;
    const float* xb = x + (size_t)b * 12288;

    // ---- issue x loads for subslice 0 (lane t owns 32 contiguous floats) ----
    float xv[32];
    {
        const float4* xq = (const float4*)xb + t * 8;
#pragma unroll
        for (int i = 0; i < 8; ++i) {
            const float4 v = xq[i];
            xv[i*4+0] = v.x; xv[i*4+1] = v.y; xv[i*4+2] = v.z; xv[i*4+3] = v.w;
        }
    }

    // ---- non-uniformly-indexed weights to LDS ----
    smem[WC3 + t] = g3[t];  smem[WC3 + 64 + t] = g3[64 + t];
    smem[WC2 + t] = g2[t];  smem[WC2 + 64 + t] = g2[64 + t];
    if (t < 32) smem[WU1 + t] = u1[t];
    __syncthreads();  // weights ready

    const int h = t & 1;       // n4-half owned by this lane
    const int p = t >> 1;      // subslice-local prefix (n2l*8 + n3)

    float regT4[36];           // [jj(4)][n1(3)*3+q1(3)] accumulated across slices
#pragma unroll
    for (int i = 0; i < 36; ++i) regT4[i] = 0.f;

#pragma unroll
    for (int n1 = 0; n1 < 3; ++n1) {
#pragma unroll
        for (int n2h = 0; n2h < 2; ++n2h) {
            const int s = n1 * 2 + n2h;

            // ---- step 1: t1[n4l*8 + m5*2+q4] = sum_n5 x * C4  (C4 uniform: s_load)
            float t1[32];
#pragma unroll
            for (int m5 = 0; m5 < 4; ++m5)
#pragma unroll
            for (int q4 = 0; q4 < 2; ++q4) {
                const float* w = g4 + (q4 * 4 + m5) * 8;
#pragma unroll
                for (int n4l = 0; n4l < 4; ++n4l) {
                    float sa = xv[n4l*8+0] * w[0];
#pragma unroll
                    for (int n5 = 1; n5 < 8; ++n5) sa = fmaf(xv[n4l*8+n5], w[n5], sa);
                    t1[n4l*8 + m5*2 + q4] = sa;
                }
            }

            // xv is dead: prefetch next slab INTO xv (zero extra registers;
            // latency hides under steps 2-4 + barriers of this slice).
            if (s < 5) {
                const float4* xq = (const float4*)xb + (s + 1) * 512 + t * 8;
#pragma unroll
                for (int i = 0; i < 8; ++i) {
                    const float4 v = xq[i];
                    xv[i*4+0] = v.x; xv[i*4+1] = v.y; xv[i*4+2] = v.z; xv[i*4+3] = v.w;
                }
            }

            // ---- step 2: acc[m4*4+m5] (q3 = h), contract n4 (own half, then
            //      partner's half via shfl_xor) and q4
            float acc[16];
#pragma unroll
            for (int i = 0; i < 16; ++i) acc[i] = 0.f;
#pragma unroll
            for (int pass = 0; pass < 2; ++pass) {
                const int hh = (pass == 0) ? h : (1 - h);   // n4-half of current t1
                if (pass == 1) {
#pragma unroll
                    for (int i = 0; i < 32; ++i) t1[i] = __shfl_xor(t1[i], 1);
                }
#pragma unroll
                for (int m4 = 0; m4 < 4; ++m4) {
                    const int cbase = WC3 + ((h * 4 + m4) * 8 + hh * 4) * 2;  // q3 = h
                    const float4 c0 = *(const float4*)&smem[cbase];
                    const float4 c1 = *(const float4*)&smem[cbase + 4];
                    const float cs[8] = {c0.x, c0.y, c0.z, c0.w, c1.x, c1.y, c1.z, c1.w};
#pragma unroll
                    for (int m5 = 0; m5 < 4; ++m5) {
                        float sa = acc[m4*4+m5];
#pragma unroll
                        for (int n4l = 0; n4l < 4; ++n4l)
#pragma unroll
                        for (int q4 = 0; q4 < 2; ++q4)
                            sa = fmaf(t1[n4l*8 + m5*2 + q4], cs[n4l*2 + q4], sa);
                        acc[m4*4+m5] = sa;
                    }
                }
            }

            __syncthreads();   // prior readers of T2S/T3S done
#pragma unroll
            for (int m45 = 0; m45 < 16; ++m45)
                smem[T2S + p * 36 + m45 * 2 + h] = acc[m45];
            __syncthreads();   // T2s ready

            // ---- step 3: contract n3 (half per lane) & q3 -> T3 rows
            {
                const int n3h = t & 1;
                const int q2  = (t >> 1) & 1;
                const int m3  = (t >> 2) & 3;
                const int n2l = t >> 4;
                float o3[16];
#pragma unroll
                for (int i = 0; i < 16; ++i) o3[i] = 0.f;
#pragma unroll
                for (int n3l = 0; n3l < 4; ++n3l) {
                    const int rb = T2S + (n2l * 8 + n3h * 4 + n3l) * 36;
                    float rv[32];
#pragma unroll
                    for (int g = 0; g < 8; ++g) {
                        const float4 v = *(const float4*)&smem[rb + g * 4];
                        rv[g*4+0] = v.x; rv[g*4+1] = v.y; rv[g*4+2] = v.z; rv[g*4+3] = v.w;
                    }
                    const int wb = WC2 + ((q2 * 4 + m3) * 8 + n3h * 4 + n3l) * 2;
                    const float w0 = smem[wb], w1 = smem[wb + 1];
#pragma unroll
                    for (int m45 = 0; m45 < 16; ++m45)
                        o3[m45] = fmaf(rv[m45*2], w0, fmaf(rv[m45*2+1], w1, o3[m45]));
                }
#pragma unroll
                for (int k = 0; k < 16; ++k) o3[k] += __shfl_xor(o3[k], 1);
                const int row = n2h * 16 + n2l * 4 + m3;   // = n2*4 + m3
#pragma unroll
                for (int k = 0; k < 8; ++k) {
                    const float v = n3h ? o3[8 + k] : o3[k];
                    smem[T3S + row * 34 + (n3h * 8 + k) * 2 + q2] = v;
                }
            }
        } // n2h
        __syncthreads();   // T3 complete for this n1

        // ---- step 4: contract n2,q2 -> regT4 (C1 uniform: s_load)
        {
            const int m3 = t >> 4, m4 = (t >> 2) & 3, m5 = t & 3;
            float2 zz[8];
#pragma unroll
            for (int n2 = 0; n2 < 8; ++n2)
                zz[n2] = *(const float2*)&smem[T3S + (n2 * 4 + m3) * 34 + (m4 * 4 + m5) * 2];
#pragma unroll
            for (int jj = 0; jj < 4; ++jj)
#pragma unroll
            for (int q1 = 0; q1 < 3; ++q1) {
                float sa = regT4[jj * 9 + n1 * 3 + q1];
#pragma unroll
                for (int n2g = 0; n2g < 4; ++n2g) {
                    const float4 w = *(const float4*)(g1 + ((q1 * 4 + jj) * 8 + n2g * 2) * 2);
                    sa = fmaf(zz[n2g*2].x,   w.x, sa);
                    sa = fmaf(zz[n2g*2].y,   w.y, sa);
                    sa = fmaf(zz[n2g*2+1].x, w.z, sa);
                    sa = fmaf(zz[n2g*2+1].y, w.w, sa);
                }
                regT4[jj * 9 + n1 * 3 + q1] = sa;
            }
        }
    } // n1
    __syncthreads();   // T3 reads done; h1 may overwrite T2S/T3S zone

    // ---- step 5: contract n1,q1 + bias + relu -> h1 (C0 uniform: s_load)
#pragma unroll
    for (int jj = 0; jj < 4; ++jj) {
        float bia[8];
#pragma unroll
        for (int m1 = 0; m1 < 8; ++m1) bia[m1] = b1g[m1 * 256 + jj * 64 + t];
#pragma unroll
        for (int m1 = 0; m1 < 8; ++m1) {
            float sa = bia[m1];
#pragma unroll
            for (int n1 = 0; n1 < 3; ++n1)
#pragma unroll
            for (int q1 = 0; q1 < 3; ++q1)
                sa = fmaf(regT4[jj * 9 + n1 * 3 + q1], g0[(m1 * 3 + n1) * 3 + q1], sa);
            smem[H1O + m1 * 256 + jj * 64 + t] = fmaxf(sa, 0.f);
        }
    }
    __syncthreads();

    // ================= layer 2 (right-to-left) =================
    // L2ab fused: per p3 read h1[16] from LDS, apply u4 (L2a) in registers,
    // contract n4,q4 (L2b) -> B row. A-buffer and one barrier eliminated.
#pragma unroll
    for (int pq = 0; pq < 2; ++pq) {
        const int p3 = 2 * t + pq;
        float o[8];
#pragma unroll
        for (int i = 0; i < 8; ++i) o[i] = 0.f;
#pragma unroll
        for (int n4 = 0; n4 < 4; ++n4) {
            const float4 hv = *(const float4*)&smem[H1O + (p3 * 4 + n4) * 4];
            const float ax = hv.x*u4[0]  + hv.y*u4[1]  + hv.z*u4[2]  + hv.w*u4[3];   // m5=0,q4=0
            const float ay = hv.x*u4[8]  + hv.y*u4[9]  + hv.z*u4[10] + hv.w*u4[11];  // m5=0,q4=1
            const float az = hv.x*u4[4]  + hv.y*u4[5]  + hv.z*u4[6]  + hv.w*u4[7];   // m5=1,q4=0
            const float aw = hv.x*u4[12] + hv.y*u4[13] + hv.z*u4[14] + hv.w*u4[15];  // m5=1,q4=1
#pragma unroll
            for (int q4 = 0; q4 < 2; ++q4) {
                const float a0 = q4 ? ay : ax;   // m5=0
                const float a1 = q4 ? aw : az;   // m5=1
#pragma unroll
                for (int q3 = 0; q3 < 2; ++q3)
#pragma unroll
                for (int m4 = 0; m4 < 2; ++m4) {
                    const float w = u3[((q3 * 2 + m4) * 4 + n4) * 2 + q4];
                    o[(m4 * 2 + 0) * 2 + q3] = fmaf(a0, w, o[(m4 * 2 + 0) * 2 + q3]);
                    o[(m4 * 2 + 1) * 2 + q3] = fmaf(a1, w, o[(m4 * 2 + 1) * 2 + q3]);
                }
            }
        }
#pragma unroll
        for (int k = 0; k < 8; ++k) smem[BO + p3 * 9 + k] = o[k];
    }
    __syncthreads();

    // L2c: contract n3(4),q3 -> C[p2][(m3*4+m45)*2+q2]  (U2 uniform)
    if (t < 32) {
        float o[16];
#pragma unroll
        for (int i = 0; i < 16; ++i) o[i] = 0.f;
#pragma unroll
        for (int n3 = 0; n3 < 4; ++n3)
#pragma unroll
        for (int q3 = 0; q3 < 2; ++q3) {
            float zb[4];
#pragma unroll
            for (int m45 = 0; m45 < 4; ++m45)
                zb[m45] = smem[BO + (t * 4 + n3) * 9 + m45 * 2 + q3];
#pragma unroll
            for (int m3 = 0; m3 < 2; ++m3)
#pragma unroll
            for (int q2 = 0; q2 < 2; ++q2) {
                const float w = u2[((q2 * 2 + m3) * 4 + n3) * 2 + q3];
#pragma unroll
                for (int m45 = 0; m45 < 4; ++m45)
                    o[(m3 * 4 + m45) * 2 + q2] = fmaf(zb[m45], w, o[(m3 * 4 + m45) * 2 + q2]);
            }
        }
#pragma unroll
        for (int k = 0; k < 16; ++k) smem[CO + t * 17 + k] = o[k];
    }
    __syncthreads();

    // L2d: contract n2(4),q2 -> D[s][n1*2+q1]  (U1 non-uniform: LDS)
    if (t < 32) {
        const int n1 = t >> 2, m2 = (t >> 1) & 1, m3 = t & 1;
        float o[8];
#pragma unroll
        for (int i = 0; i < 8; ++i) o[i] = 0.f;
#pragma unroll
        for (int n2 = 0; n2 < 4; ++n2)
#pragma unroll
        for (int q2 = 0; q2 < 2; ++q2) {
            float cb[4];
#pragma unroll
            for (int m45 = 0; m45 < 4; ++m45)
                cb[m45] = smem[CO + (n1 * 4 + n2) * 17 + (m3 * 4 + m45) * 2 + q2];
#pragma unroll
            for (int q1 = 0; q1 < 2; ++q1) {
                const float w = smem[WU1 + ((q1 * 2 + m2) * 4 + n2) * 2 + q2];
#pragma unroll
                for (int m45 = 0; m45 < 4; ++m45)
                    o[m45 * 2 + q1] = fmaf(cb[m45], w, o[m45 * 2 + q1]);
            }
        }
#pragma unroll
        for (int m45 = 0; m45 < 4; ++m45)
#pragma unroll
        for (int q1 = 0; q1 < 2; ++q1)
            smem[DO + (m2 * 8 + m3 * 4 + m45) * 17 + n1 * 2 + q1] = o[m45 * 2 + q1];
    }
    __syncthreads();

    // L2e: contract n1(8),q1 + bias + relu -> h2  (U0 uniform)
    if (t < 16) {
        float o[4];
#pragma unroll
        for (int i = 0; i < 4; ++i) o[i] = 0.f;
#pragma unroll
        for (int n1 = 0; n1 < 8; ++n1)
#pragma unroll
        for (int q1 = 0; q1 < 2; ++q1) {
            const float dv = smem[DO + t * 17 + n1 * 2 + q1];
#pragma unroll
            for (int m1 = 0; m1 < 4; ++m1)
                o[m1] = fmaf(dv, u0[(m1 * 8 + n1) * 2 + q1], o[m1]);
        }
#pragma unroll
        for (int m1 = 0; m1 < 4; ++m1)
            smem[H2O + m1 * 16 + t] = fmaxf(o[m1] + b2g[m1 * 16 + t], 0.f);
    }
    __syncthreads();

    // ---- layer 3 dense (W3 32x64 from d_ws) + relu ----
    if (t < 32) {
        const float4* wr = (const float4*)(w3g + t * 64);
        float sa = b3g[t];
#pragma unroll
        for (int g = 0; g < 16; ++g) {
            const float4 w4 = wr[g];
            sa = fmaf(w4.x, smem[H2O + g*4 + 0],
                 fmaf(w4.y, smem[H2O + g*4 + 1],
                 fmaf(w4.z, smem[H2O + g*4 + 2],
                 fmaf(w4.w, smem[H2O + g*4 + 3], sa))));
        }
        smem[H3O + t] = fmaxf(sa, 0.f);
    }
    __syncthreads();

    // ---- head: logits + log_softmax ----
    {
        const int k = t & 31;
        float pr = smem[H3O + k] * Wmg[t];   // t = c*32 + k
#pragma unroll
        for (int d = 16; d >= 1; d >>= 1) pr += __shfl_xor(pr, d);
        const float l0 = __shfl(pr, 0) + blg[0];
        const float l1 = __shfl(pr, 32) + blg[1];
        if (t == 0) {
            const float mm = fmaxf(l0, l1);
            const float lse = mm + logf(expf(l0 - mm) + expf(l1 - mm));
            out[(size_t)b * 2 + 0] = l0 - lse;
            out[(size_t)b * 2 + 1] = l1 - lse;
        }
    }
}

extern "C" void kernel_launch(void* const* d_in, const int* in_sizes, int n_in,
                              void* d_out, int out_size, void* d_ws, size_t ws_size,
                              hipStream_t stream) {
    const float* x    = (const float*)d_in[0];
    const float* l1c0 = (const float*)d_in[1];
    const float* l1c1 = (const float*)d_in[2];
    const float* l1c2 = (const float*)d_in[3];
    const float* l1c3 = (const float*)d_in[4];
    const float* l1c4 = (const float*)d_in[5];
    const float* b1   = (const float*)d_in[6];
    const float* l2c0 = (const float*)d_in[7];
    const float* l2c1 = (const float*)d_in[8];
    const float* l2c2 = (const float*)d_in[9];
    const float* l2c3 = (const float*)d_in[10];
    const float* l2c4 = (const float*)d_in[11];
    const float* b2   = (const float*)d_in[12];
    const float* l3c0 = (const float*)d_in[13];
    const float* l3c1 = (const float*)d_in[14];
    const float* l3c2 = (const float*)d_in[15];
    const float* l3c3 = (const float*)d_in[16];
    const float* l3c4 = (const float*)d_in[17];
    const float* b3   = (const float*)d_in[18];
    const float* Wm   = (const float*)d_in[19];
    const float* bl   = (const float*)d_in[20];
    float* W3 = (float*)d_ws;  // 2048 floats scratch

    tt_setup_w3<<<8, 256, 0, stream>>>(l3c0, l3c1, l3c2, l3c3, l3c4, W3);
    tt_main<<<2048, 64, 0, stream>>>(x, l1c0, l1c1, l1c2, l1c3, l1c4, b1,
                                     l2c0, l2c1, l2c2, l2c3, l2c4, b2, b3,
                                     Wm, bl, W3, (float*)d_out);
}

// Round 15
// 204.245 us; speedup vs baseline: 1.0694x; 1.0656x over previous
//
#include <hip/hip_runtime.h>
#include <math.h>

// ---------------- LDS layout (floats), per 64-thread (1-wave) block ----------
// Session-final structure (13 rounds of restructuring all land at/above this):
// R0 layout minus the A-buffer (L2ab fused), in-place x prefetch,
// waves_per_eu(1,2) allocator pin (spills 38MB->64KB), and layer-3 computed
// by direct TT contraction in the tail (second kernel launch eliminated).
#define WC3  0      // l1c3 [q3][m4][n4][q4]            128
#define WC2  128    // l1c2 [q2][m3][n3][q3]            128
#define WU1  256    // l2c1                              32  -> 288
#define T2S  288    // [32 prefixes][36]  (pad 36: b128-aligned rows)  1152 -> 1440
#define T3S  1440   // [32 rows][34]      (pad 34: b64-aligned)        1088 -> 2528
#define H1O  288    // h1 (2048) overlays T2S/T3S after layer-1 slices  -> 2336
#define BO   2528   // B[128][9] = 1152 (after T3S; h1 stays live)      -> 3680
#define CO   1440   // C[32][17] = 544  (h1/T3 dead by L2c)
#define DO   1984   // D[16][17] = 272
#define H2O  2256   // 64
#define H3O  2320   // 32 -> 2352
#define LDS_FLOATS 3680   // 14720 B; grid caps residency at 8 waves/CU

// Grid = 2048 one-wave blocks / 256 CU = 8 waves/CU = 2 waves/EU (hard cap).
// waves_per_eu(1,2): tell the allocator exactly that, so it stops squeezing
// VGPRs toward 6-8 waves/EU (validated R7: scratch spills 38 MB -> 64 KB).
__global__ __launch_bounds__(64)
__attribute__((amdgpu_waves_per_eu(1, 2)))
void tt_main(const float* __restrict__ x,
             const float* __restrict__ g0, const float* __restrict__ g1,
             const float* __restrict__ g2, const float* __restrict__ g3,
             const float* __restrict__ g4, const float* __restrict__ b1g,
             const float* __restrict__ u0, const float* __restrict__ u1,
             const float* __restrict__ u2, const float* __restrict__ u3,
             const float* __restrict__ u4, const float* __restrict__ b2g,
             const float* __restrict__ v0, const float* __restrict__ v1,
             const float* __restrict__ v2, const float* __restrict__ v3,
             const float* __restrict__ v4, const float* __restrict__ b3g,
             const float* __restrict__ Wmg, const float* __restrict__ blg,
             float* __restrict__ out)
{
    __shared__ float smem[LDS_FLOATS];
    const int t = threadIdx.x;
    const int b = blockIdx.x;
    const float* xb = x + (size_t)b * 12288;

    // ---- issue x loads for subslice 0 (lane t owns 32 contiguous floats) ----
    float xv[32];
    {
        const float4* xq = (const float4*)xb + t * 8;
#pragma unroll
        for (int i = 0; i < 8; ++i) {
            const float4 v = xq[i];
            xv[i*4+0] = v.x; xv[i*4+1] = v.y; xv[i*4+2] = v.z; xv[i*4+3] = v.w;
        }
    }

    // ---- non-uniformly-indexed weights to LDS ----
    smem[WC3 + t] = g3[t];  smem[WC3 + 64 + t] = g3[64 + t];
    smem[WC2 + t] = g2[t];  smem[WC2 + 64 + t] = g2[64 + t];
    if (t < 32) smem[WU1 + t] = u1[t];
    __syncthreads();  // weights ready

    const int h = t & 1;       // n4-half owned by this lane
    const int p = t >> 1;      // subslice-local prefix (n2l*8 + n3)

    float regT4[36];           // [jj(4)][n1(3)*3+q1(3)] accumulated across slices
#pragma unroll
    for (int i = 0; i < 36; ++i) regT4[i] = 0.f;

#pragma unroll
    for (int n1 = 0; n1 < 3; ++n1) {
#pragma unroll
        for (int n2h = 0; n2h < 2; ++n2h) {
            const int s = n1 * 2 + n2h;

            // ---- step 1: t1[n4l*8 + m5*2+q4] = sum_n5 x * C4  (C4 uniform: s_load)
            float t1[32];
#pragma unroll
            for (int m5 = 0; m5 < 4; ++m5)
#pragma unroll
            for (int q4 = 0; q4 < 2; ++q4) {
                const float* w = g4 + (q4 * 4 + m5) * 8;
#pragma unroll
                for (int n4l = 0; n4l < 4; ++n4l) {
                    float sa = xv[n4l*8+0] * w[0];
#pragma unroll
                    for (int n5 = 1; n5 < 8; ++n5) sa = fmaf(xv[n4l*8+n5], w[n5], sa);
                    t1[n4l*8 + m5*2 + q4] = sa;
                }
            }

            // xv is dead: prefetch next slab INTO xv (zero extra registers;
            // latency hides under steps 2-4 + barriers of this slice).
            if (s < 5) {
                const float4* xq = (const float4*)xb + (s + 1) * 512 + t * 8;
#pragma unroll
                for (int i = 0; i < 8; ++i) {
                    const float4 v = xq[i];
                    xv[i*4+0] = v.x; xv[i*4+1] = v.y; xv[i*4+2] = v.z; xv[i*4+3] = v.w;
                }
            }

            // ---- step 2: acc[m4*4+m5] (q3 = h), contract n4 (own half, then
            //      partner's half via shfl_xor) and q4
            float acc[16];
#pragma unroll
            for (int i = 0; i < 16; ++i) acc[i] = 0.f;
#pragma unroll
            for (int pass = 0; pass < 2; ++pass) {
                const int hh = (pass == 0) ? h : (1 - h);   // n4-half of current t1
                if (pass == 1) {
#pragma unroll
                    for (int i = 0; i < 32; ++i) t1[i] = __shfl_xor(t1[i], 1);
                }
#pragma unroll
                for (int m4 = 0; m4 < 4; ++m4) {
                    const int cbase = WC3 + ((h * 4 + m4) * 8 + hh * 4) * 2;  // q3 = h
                    const float4 c0 = *(const float4*)&smem[cbase];
                    const float4 c1 = *(const float4*)&smem[cbase + 4];
                    const float cs[8] = {c0.x, c0.y, c0.z, c0.w, c1.x, c1.y, c1.z, c1.w};
#pragma unroll
                    for (int m5 = 0; m5 < 4; ++m5) {
                        float sa = acc[m4*4+m5];
#pragma unroll
                        for (int n4l = 0; n4l < 4; ++n4l)
#pragma unroll
                        for (int q4 = 0; q4 < 2; ++q4)
                            sa = fmaf(t1[n4l*8 + m5*2 + q4], cs[n4l*2 + q4], sa);
                        acc[m4*4+m5] = sa;
                    }
                }
            }

            __syncthreads();   // prior readers of T2S/T3S done
#pragma unroll
            for (int m45 = 0; m45 < 16; ++m45)
                smem[T2S + p * 36 + m45 * 2 + h] = acc[m45];
            __syncthreads();   // T2s ready

            // ---- step 3: contract n3 (half per lane) & q3 -> T3 rows
            {
                const int n3h = t & 1;
                const int q2  = (t >> 1) & 1;
                const int m3  = (t >> 2) & 3;
                const int n2l = t >> 4;
                float o3[16];
#pragma unroll
                for (int i = 0; i < 16; ++i) o3[i] = 0.f;
#pragma unroll
                for (int n3l = 0; n3l < 4; ++n3l) {
                    const int rb = T2S + (n2l * 8 + n3h * 4 + n3l) * 36;
                    float rv[32];
#pragma unroll
                    for (int g = 0; g < 8; ++g) {
                        const float4 v = *(const float4*)&smem[rb + g * 4];
                        rv[g*4+0] = v.x; rv[g*4+1] = v.y; rv[g*4+2] = v.z; rv[g*4+3] = v.w;
                    }
                    const int wb = WC2 + ((q2 * 4 + m3) * 8 + n3h * 4 + n3l) * 2;
                    const float w0 = smem[wb], w1 = smem[wb + 1];
#pragma unroll
                    for (int m45 = 0; m45 < 16; ++m45)
                        o3[m45] = fmaf(rv[m45*2], w0, fmaf(rv[m45*2+1], w1, o3[m45]));
                }
#pragma unroll
                for (int k = 0; k < 16; ++k) o3[k] += __shfl_xor(o3[k], 1);
                const int row = n2h * 16 + n2l * 4 + m3;   // = n2*4 + m3
#pragma unroll
                for (int k = 0; k < 8; ++k) {
                    const float v = n3h ? o3[8 + k] : o3[k];
                    smem[T3S + row * 34 + (n3h * 8 + k) * 2 + q2] = v;
                }
            }
        } // n2h
        __syncthreads();   // T3 complete for this n1

        // ---- step 4: contract n2,q2 -> regT4 (C1 uniform: s_load)
        {
            const int m3 = t >> 4, m4 = (t >> 2) & 3, m5 = t & 3;
            float2 zz[8];
#pragma unroll
            for (int n2 = 0; n2 < 8; ++n2)
                zz[n2] = *(const float2*)&smem[T3S + (n2 * 4 + m3) * 34 + (m4 * 4 + m5) * 2];
#pragma unroll
            for (int jj = 0; jj < 4; ++jj)
#pragma unroll
            for (int q1 = 0; q1 < 3; ++q1) {
                float sa = regT4[jj * 9 + n1 * 3 + q1];
#pragma unroll
                for (int n2g = 0; n2g < 4; ++n2g) {
                    const float4 w = *(const float4*)(g1 + ((q1 * 4 + jj) * 8 + n2g * 2) * 2);
                    sa = fmaf(zz[n2g*2].x,   w.x, sa);
                    sa = fmaf(zz[n2g*2].y,   w.y, sa);
                    sa = fmaf(zz[n2g*2+1].x, w.z, sa);
                    sa = fmaf(zz[n2g*2+1].y, w.w, sa);
                }
                regT4[jj * 9 + n1 * 3 + q1] = sa;
            }
        }
    } // n1
    __syncthreads();   // T3 reads done; h1 may overwrite T2S/T3S zone

    // ---- step 5: contract n1,q1 + bias + relu -> h1 (C0 uniform: s_load)
#pragma unroll
    for (int jj = 0; jj < 4; ++jj) {
        float bia[8];
#pragma unroll
        for (int m1 = 0; m1 < 8; ++m1) bia[m1] = b1g[m1 * 256 + jj * 64 + t];
#pragma unroll
        for (int m1 = 0; m1 < 8; ++m1) {
            float sa = bia[m1];
#pragma unroll
            for (int n1 = 0; n1 < 3; ++n1)
#pragma unroll
            for (int q1 = 0; q1 < 3; ++q1)
                sa = fmaf(regT4[jj * 9 + n1 * 3 + q1], g0[(m1 * 3 + n1) * 3 + q1], sa);
            smem[H1O + m1 * 256 + jj * 64 + t] = fmaxf(sa, 0.f);
        }
    }
    __syncthreads();

    // ================= layer 2 (right-to-left) =================
    // L2ab fused: per p3 read h1[16] from LDS, apply u4 (L2a) in registers,
    // contract n4,q4 (L2b) -> B row. A-buffer and one barrier eliminated.
#pragma unroll
    for (int pq = 0; pq < 2; ++pq) {
        const int p3 = 2 * t + pq;
        float o[8];
#pragma unroll
        for (int i = 0; i < 8; ++i) o[i] = 0.f;
#pragma unroll
        for (int n4 = 0; n4 < 4; ++n4) {
            const float4 hv = *(const float4*)&smem[H1O + (p3 * 4 + n4) * 4];
            const float ax = hv.x*u4[0]  + hv.y*u4[1]  + hv.z*u4[2]  + hv.w*u4[3];   // m5=0,q4=0
            const float ay = hv.x*u4[8]  + hv.y*u4[9]  + hv.z*u4[10] + hv.w*u4[11];  // m5=0,q4=1
            const float az = hv.x*u4[4]  + hv.y*u4[5]  + hv.z*u4[6]  + hv.w*u4[7];   // m5=1,q4=0
            const float aw = hv.x*u4[12] + hv.y*u4[13] + hv.z*u4[14] + hv.w*u4[15];  // m5=1,q4=1
#pragma unroll
            for (int q4 = 0; q4 < 2; ++q4) {
                const float a0 = q4 ? ay : ax;   // m5=0
                const float a1 = q4 ? aw : az;   // m5=1
#pragma unroll
                for (int q3 = 0; q3 < 2; ++q3)
#pragma unroll
                for (int m4 = 0; m4 < 2; ++m4) {
                    const float w = u3[((q3 * 2 + m4) * 4 + n4) * 2 + q4];
                    o[(m4 * 2 + 0) * 2 + q3] = fmaf(a0, w, o[(m4 * 2 + 0) * 2 + q3]);
                    o[(m4 * 2 + 1) * 2 + q3] = fmaf(a1, w, o[(m4 * 2 + 1) * 2 + q3]);
                }
            }
        }
#pragma unroll
        for (int k = 0; k < 8; ++k) smem[BO + p3 * 9 + k] = o[k];
    }
    __syncthreads();

    // L2c: contract n3(4),q3 -> C[p2][(m3*4+m45)*2+q2]  (U2 uniform)
    if (t < 32) {
        float o[16];
#pragma unroll
        for (int i = 0; i < 16; ++i) o[i] = 0.f;
#pragma unroll
        for (int n3 = 0; n3 < 4; ++n3)
#pragma unroll
        for (int q3 = 0; q3 < 2; ++q3) {
            float zb[4];
#pragma unroll
            for (int m45 = 0; m45 < 4; ++m45)
                zb[m45] = smem[BO + (t * 4 + n3) * 9 + m45 * 2 + q3];
#pragma unroll
            for (int m3 = 0; m3 < 2; ++m3)
#pragma unroll
            for (int q2 = 0; q2 < 2; ++q2) {
                const float w = u2[((q2 * 2 + m3) * 4 + n3) * 2 + q3];
#pragma unroll
                for (int m45 = 0; m45 < 4; ++m45)
                    o[(m3 * 4 + m45) * 2 + q2] = fmaf(zb[m45], w, o[(m3 * 4 + m45) * 2 + q2]);
            }
        }
#pragma unroll
        for (int k = 0; k < 16; ++k) smem[CO + t * 17 + k] = o[k];
    }
    __syncthreads();

    // L2d: contract n2(4),q2 -> D[s][n1*2+q1]  (U1 non-uniform: LDS)
    if (t < 32) {
        const int n1 = t >> 2, m2 = (t >> 1) & 1, m3 = t & 1;
        float o[8];
#pragma unroll
        for (int i = 0; i < 8; ++i) o[i] = 0.f;
#pragma unroll
        for (int n2 = 0; n2 < 4; ++n2)
#pragma unroll
        for (int q2 = 0; q2 < 2; ++q2) {
            float cb[4];
#pragma unroll
            for (int m45 = 0; m45 < 4; ++m45)
                cb[m45] = smem[CO + (n1 * 4 + n2) * 17 + (m3 * 4 + m45) * 2 + q2];
#pragma unroll
            for (int q1 = 0; q1 < 2; ++q1) {
                const float w = smem[WU1 + ((q1 * 2 + m2) * 4 + n2) * 2 + q2];
#pragma unroll
                for (int m45 = 0; m45 < 4; ++m45)
                    o[m45 * 2 + q1] = fmaf(cb[m45], w, o[m45 * 2 + q1]);
            }
        }
#pragma unroll
        for (int m45 = 0; m45 < 4; ++m45)
#pragma unroll
        for (int q1 = 0; q1 < 2; ++q1)
            smem[DO + (m2 * 8 + m3 * 4 + m45) * 17 + n1 * 2 + q1] = o[m45 * 2 + q1];
    }
    __syncthreads();

    // L2e: contract n1(8),q1 + bias + relu -> h2  (U0 uniform)
    if (t < 16) {
        float o[4];
#pragma unroll
        for (int i = 0; i < 4; ++i) o[i] = 0.f;
#pragma unroll
        for (int n1 = 0; n1 < 8; ++n1)
#pragma unroll
        for (int q1 = 0; q1 < 2; ++q1) {
            const float dv = smem[DO + t * 17 + n1 * 2 + q1];
#pragma unroll
            for (int m1 = 0; m1 < 4; ++m1)
                o[m1] = fmaf(dv, u0[(m1 * 8 + n1) * 2 + q1], o[m1]);
        }
#pragma unroll
        for (int m1 = 0; m1 < 4; ++m1)
            smem[H2O + m1 * 16 + t] = fmaxf(o[m1] + b2g[m1 * 16 + t], 0.f);
    }
    __syncthreads();

    // ---- layer 3: direct TT contraction + relu (replaces precomputed W3;
    //      second kernel launch eliminated). Lane t<32 computes output mi=t
    //      via right-to-left chain A4->A3->A2->A1->y. Same product multiset
    //      as the old W3 precompute (only fp association differs). All
    //      register indices compile-time (rule #20); h2 reads are broadcast.
    if (t < 32) {
        const int m1 = (t >> 4) & 1, m2 = (t >> 3) & 1, m3 = (t >> 2) & 1,
                  m4 = (t >> 1) & 1, m5 = t & 1;
        // per-lane core slices (tiny, L1-resident)
        float g4c[2][2];      // [q4][n5]
#pragma unroll
        for (int q4 = 0; q4 < 2; ++q4)
#pragma unroll
        for (int n5 = 0; n5 < 2; ++n5)
            g4c[q4][n5] = v4[(q4 * 2 + m5) * 2 + n5];
        float g3c[2][2][2];   // [q3][n4][q4]
#pragma unroll
        for (int q3 = 0; q3 < 2; ++q3)
#pragma unroll
        for (int n4 = 0; n4 < 2; ++n4)
#pragma unroll
        for (int q4 = 0; q4 < 2; ++q4)
            g3c[q3][n4][q4] = v3[((q3 * 2 + m4) * 2 + n4) * 2 + q4];
        float g2c[2][2][2];   // [q2][n3][q3]
#pragma unroll
        for (int q2 = 0; q2 < 2; ++q2)
#pragma unroll
        for (int n3 = 0; n3 < 2; ++n3)
#pragma unroll
        for (int q3 = 0; q3 < 2; ++q3)
            g2c[q2][n3][q3] = v2[((q2 * 2 + m3) * 2 + n3) * 2 + q3];
        float g1c[2][2][2];   // [q1][n2][q2]
#pragma unroll
        for (int q1 = 0; q1 < 2; ++q1)
#pragma unroll
        for (int n2 = 0; n2 < 2; ++n2)
#pragma unroll
        for (int q2 = 0; q2 < 2; ++q2)
            g1c[q1][n2][q2] = v1[((q1 * 2 + m2) * 2 + n2) * 2 + q2];
        float g0c[4][2];      // [n1][q1]
#pragma unroll
        for (int n1 = 0; n1 < 4; ++n1)
#pragma unroll
        for (int q1 = 0; q1 < 2; ++q1)
            g0c[n1][q1] = v0[(m1 * 4 + n1) * 2 + q1];

        // A3[q3][pp3], pp3 = n1n2n3 (16); h2 streamed per-pp3 (4 floats live)
        float A3[2][16];
#pragma unroll
        for (int pp = 0; pp < 16; ++pp) {
            const float4 hv = *(const float4*)&smem[H2O + pp * 4];  // broadcast
            float a4[2][2];   // [q4][n4]
#pragma unroll
            for (int q4 = 0; q4 < 2; ++q4) {
                a4[q4][0] = hv.x * g4c[q4][0] + hv.y * g4c[q4][1];
                a4[q4][1] = hv.z * g4c[q4][0] + hv.w * g4c[q4][1];
            }
#pragma unroll
            for (int q3 = 0; q3 < 2; ++q3) {
                float s3 = 0.f;
#pragma unroll
                for (int n4 = 0; n4 < 2; ++n4)
#pragma unroll
                for (int q4 = 0; q4 < 2; ++q4)
                    s3 = fmaf(g3c[q3][n4][q4], a4[q4][n4], s3);
                A3[q3][pp] = s3;
            }
        }
        // A2[q2][pp2], pp2 = n1n2 (8)
        float A2[2][8];
#pragma unroll
        for (int pp = 0; pp < 8; ++pp)
#pragma unroll
        for (int q2 = 0; q2 < 2; ++q2) {
            float s2 = 0.f;
#pragma unroll
            for (int n3 = 0; n3 < 2; ++n3)
#pragma unroll
            for (int q3 = 0; q3 < 2; ++q3)
                s2 = fmaf(g2c[q2][n3][q3], A3[q3][pp * 2 + n3], s2);
            A2[q2][pp] = s2;
        }
        // A1[q1][n1] (4)
        float A1[2][4];
#pragma unroll
        for (int pp = 0; pp < 4; ++pp)
#pragma unroll
        for (int q1 = 0; q1 < 2; ++q1) {
            float s1 = 0.f;
#pragma unroll
            for (int n2 = 0; n2 < 2; ++n2)
#pragma unroll
            for (int q2 = 0; q2 < 2; ++q2)
                s1 = fmaf(g1c[q1][n2][q2], A2[q2][pp * 2 + n2], s1);
            A1[q1][pp] = s1;
        }
        // y = bias + contract n1,q1; relu
        float sa = b3g[t];
#pragma unroll
        for (int n1 = 0; n1 < 4; ++n1)
#pragma unroll
        for (int q1 = 0; q1 < 2; ++q1)
            sa = fmaf(g0c[n1][q1], A1[q1][n1], sa);
        smem[H3O + t] = fmaxf(sa, 0.f);
    }
    __syncthreads();

    // ---- head: logits + log_softmax ----
    {
        const int k = t & 31;
        float pr = smem[H3O + k] * Wmg[t];   // t = c*32 + k
#pragma unroll
        for (int d = 16; d >= 1; d >>= 1) pr += __shfl_xor(pr, d);
        const float l0 = __shfl(pr, 0) + blg[0];
        const float l1 = __shfl(pr, 32) + blg[1];
        if (t == 0) {
            const float mm = fmaxf(l0, l1);
            const float lse = mm + logf(expf(l0 - mm) + expf(l1 - mm));
            out[(size_t)b * 2 + 0] = l0 - lse;
            out[(size_t)b * 2 + 1] = l1 - lse;
        }
    }
}

extern "C" void kernel_launch(void* const* d_in, const int* in_sizes, int n_in,
                              void* d_out, int out_size, void* d_ws, size_t ws_size,
                              hipStream_t stream) {
    const float* x    = (const float*)d_in[0];
    const float* l1c0 = (const float*)d_in[1];
    const float* l1c1 = (const float*)d_in[2];
    const float* l1c2 = (const float*)d_in[3];
    const float* l1c3 = (const float*)d_in[4];
    const float* l1c4 = (const float*)d_in[5];
    const float* b1   = (const float*)d_in[6];
    const float* l2c0 = (const float*)d_in[7];
    const float* l2c1 = (const float*)d_in[8];
    const float* l2c2 = (const float*)d_in[9];
    const float* l2c3 = (const float*)d_in[10];
    const float* l2c4 = (const float*)d_in[11];
    const float* b2   = (const float*)d_in[12];
    const float* l3c0 = (const float*)d_in[13];
    const float* l3c1 = (const float*)d_in[14];
    const float* l3c2 = (const float*)d_in[15];
    const float* l3c3 = (const float*)d_in[16];
    const float* l3c4 = (const float*)d_in[17];
    const float* b3   = (const float*)d_in[18];
    const float* Wm   = (const float*)d_in[19];
    const float* bl   = (const float*)d_in[20];
    (void)d_ws; (void)ws_size;  // W3 precompute eliminated

    tt_main<<<2048, 64, 0, stream>>>(x, l1c0, l1c1, l1c2, l1c3, l1c4, b1,
                                     l2c0, l2c1, l2c2, l2c3, l2c4, b2,
                                     l3c0, l3c1, l3c2, l3c3, l3c4, b3,
                                     Wm, bl, (float*)d_out);
}